// Round 1
// 266.413 us; speedup vs baseline: 1.0098x; 1.0098x over previous
//
#include <hip/hip_runtime.h>
#include <hip/hip_bf16.h>
#include <math.h>

#define LDIM 4096
#define NROWS 8192
#define NOUT 512

static const float SQRT_HALF_F = 0.70710678118654752440f;

typedef __attribute__((ext_vector_type(8))) short short8;
typedef __attribute__((ext_vector_type(4))) float f32x4;
typedef __attribute__((ext_vector_type(8))) unsigned short u16x8;
typedef __attribute__((ext_vector_type(4))) unsigned short u16x4;
typedef __attribute__((ext_vector_type(2))) unsigned short u16x2;

// ws layout
#define AM_OFF   0ull                         // bf16 masked A: 8192*4096*2 = 67108864
#define WT_OFF   67108864ull                  // bf16 Wt (N x K): 512*4096*2 = 4194304
#define PART_OFF (WT_OFF + 4194304ull)        // double[8192*2] partials
#define THR_OFF  (PART_OFF + 131072ull)       // float[1]

__device__ inline unsigned short f2bf(float f) {
  union { float f; unsigned u; } v; v.f = f;
  unsigned r = (v.u + 0x7fffu + ((v.u >> 16) & 1u)) >> 16;
  return (unsigned short)r;
}

__device__ inline unsigned short mcvt(float f, float thr) {
  return f2bf((fabsf(f) > thr) ? f : 0.0f);
}

__device__ inline void async16(void* l, const void* g) {
  __builtin_amdgcn_global_load_lds((const __attribute__((address_space(1))) void*)g,
                                   (__attribute__((address_space(3))) void*)l, 16, 0, 0);
}

// ---------------- Kernel 1: Haar stats (blocks 0..8191) + W convert (tail) ----
// Register-resident 5-level Haar: thread t owns x[16t..16t+16); levels 1-4
// thread-local, level 5 lane-pair (shfl_xor 1). wcvt fused as tail blocks to
// save one launch (in-stream kernels serialize; wcvt was pure added latency).
__global__ __launch_bounds__(256) void haar1_kernel(const float* __restrict__ x,
                                                    double* __restrict__ partials,
                                                    const float* __restrict__ W,
                                                    unsigned short* __restrict__ Wt) {
  if (blockIdx.x >= NROWS) {
    // ---- fused wcvt: W (K x N fp32) -> Wt (N x K bf16) ----
    __shared__ float tile[32][33];
    const int wb = blockIdx.x - NROWS;
    const int bx = wb & 15;        // n tile (16)
    const int by = wb >> 4;        // k tile (128)
    const int tx = threadIdx.x & 31, ty = threadIdx.x >> 5;
#pragma unroll
    for (int j = 0; j < 4; ++j)
      tile[ty + j * 8][tx] = W[(size_t)(by * 32 + ty + j * 8) * NOUT + bx * 32 + tx];
    __syncthreads();
#pragma unroll
    for (int j = 0; j < 4; ++j)
      Wt[(size_t)(bx * 32 + ty + j * 8) * LDIM + by * 32 + tx] = f2bf(tile[tx][ty + j * 8]);
    return;
  }

  __shared__ double red[8];
  const int row = blockIdx.x;
  const int t = threadIdx.x;
  const float S = SQRT_HALF_F;

  const float4* xr = (const float4*)(x + (size_t)row * LDIM) + 4 * t;
  float v[16];
#pragma unroll
  for (int k = 0; k < 4; ++k) {
    float4 q = xr[k];
    v[4 * k] = q.x; v[4 * k + 1] = q.y; v[4 * k + 2] = q.z; v[4 * k + 3] = q.w;
  }

  double sa = 0.0, sq = 0.0;
  float a1[8], a2[4], a3[2], a4;
#pragma unroll
  for (int j = 0; j < 8; ++j) {
    float d = (v[2 * j] - v[2 * j + 1]) * S;
    a1[j] = (v[2 * j] + v[2 * j + 1]) * S;
    sa += (double)fabsf(d); sq += (double)d * (double)d;
  }
#pragma unroll
  for (int j = 0; j < 4; ++j) {
    float d = (a1[2 * j] - a1[2 * j + 1]) * S;
    a2[j] = (a1[2 * j] + a1[2 * j + 1]) * S;
    sa += (double)fabsf(d); sq += (double)d * (double)d;
  }
#pragma unroll
  for (int j = 0; j < 2; ++j) {
    float d = (a2[2 * j] - a2[2 * j + 1]) * S;
    a3[j] = (a2[2 * j] + a2[2 * j + 1]) * S;
    sa += (double)fabsf(d); sq += (double)d * (double)d;
  }
  {
    float d = (a3[0] - a3[1]) * S;
    a4 = (a3[0] + a3[1]) * S;
    sa += (double)fabsf(d); sq += (double)d * (double)d;
  }
  {
    float other = __shfl_xor(a4, 1, 64);
    if ((t & 1) == 0) {
      float d = (a4 - other) * S, ap = (a4 + other) * S;
      sa += (double)fabsf(d) + (double)fabsf(ap);
      sq += (double)d * (double)d + (double)ap * (double)ap;
    }
  }

  const int lane = t & 63, wid = t >> 6;
#pragma unroll
  for (int off = 32; off > 0; off >>= 1) {
    sa += __shfl_down(sa, off, 64);
    sq += __shfl_down(sq, off, 64);
  }
  if (lane == 0) { red[wid] = sa; red[4 + wid] = sq; }
  __syncthreads();
  if (t == 0) {
    partials[2 * (size_t)row + 0] = red[0] + red[1] + red[2] + red[3];
    partials[2 * (size_t)row + 1] = red[4] + red[5] + red[6] + red[7];
  }
}

// ---------------- Kernel 2: reduce partials -> threshold ----------------
__global__ __launch_bounds__(1024) void thr_kernel(const double* __restrict__ partials,
                                                   float* __restrict__ thr) {
  __shared__ double red[32];
  const int tid = threadIdx.x;
  double sa = 0.0, sq = 0.0;
#pragma unroll
  for (int k = 0; k < NROWS / 1024; ++k) {
    int i = tid + k * 1024;
    sa += partials[2 * i + 0];
    sq += partials[2 * i + 1];
  }
  const int lane = tid & 63, wid = tid >> 6;
#pragma unroll
  for (int off = 32; off > 0; off >>= 1) {
    sa += __shfl_down(sa, off, 64);
    sq += __shfl_down(sq, off, 64);
  }
  if (lane == 0) { red[wid] = sa; red[16 + wid] = sq; }
  __syncthreads();
  if (tid == 0) {
    double s = 0.0, q = 0.0;
#pragma unroll
    for (int i = 0; i < 16; ++i) { s += red[i]; q += red[16 + i]; }
    const double n = (double)NROWS * (double)LDIM;
    double mean = s / n;
    double var = (q - s * s / n) / (n - 1.0);
    *thr = (float)(mean + sqrt(var));
  }
}

// ---------------- Kernel 3: Haar recompute + mask + bf16 write ----------------
__global__ __launch_bounds__(256) void haar2_kernel(const float* __restrict__ x,
                                                    const float* __restrict__ thrp,
                                                    unsigned short* __restrict__ Am) {
  const float thr = *thrp;
  const int row = blockIdx.x;
  const int t = threadIdx.x;
  const float S = SQRT_HALF_F;

  const float4* xr = (const float4*)(x + (size_t)row * LDIM) + 4 * t;
  float v[16];
#pragma unroll
  for (int k = 0; k < 4; ++k) {
    float4 q = xr[k];
    v[4 * k] = q.x; v[4 * k + 1] = q.y; v[4 * k + 2] = q.z; v[4 * k + 3] = q.w;
  }

  unsigned short* orow = Am + (size_t)row * LDIM;
  float a1[8], a2[4], a3[2], a4;

  u16x8 d1;
#pragma unroll
  for (int j = 0; j < 8; ++j) {
    float d = (v[2 * j] - v[2 * j + 1]) * S;
    a1[j] = (v[2 * j] + v[2 * j + 1]) * S;
    d1[j] = mcvt(d, thr);
  }
  *(u16x8*)(orow + 2048 + 8 * t) = d1;

  u16x4 d2;
#pragma unroll
  for (int j = 0; j < 4; ++j) {
    float d = (a1[2 * j] - a1[2 * j + 1]) * S;
    a2[j] = (a1[2 * j] + a1[2 * j + 1]) * S;
    d2[j] = mcvt(d, thr);
  }
  *(u16x4*)(orow + 1024 + 4 * t) = d2;

  u16x2 d3;
#pragma unroll
  for (int j = 0; j < 2; ++j) {
    float d = (a2[2 * j] - a2[2 * j + 1]) * S;
    a3[j] = (a2[2 * j] + a2[2 * j + 1]) * S;
    d3[j] = mcvt(d, thr);
  }
  *(u16x2*)(orow + 512 + 2 * t) = d3;

  {
    float d = (a3[0] - a3[1]) * S;
    a4 = (a3[0] + a3[1]) * S;
    orow[256 + t] = mcvt(d, thr);
  }
  {
    float other = __shfl_xor(a4, 1, 64);
    if ((t & 1) == 0) {
      float d = (a4 - other) * S, ap = (a4 + other) * S;
      orow[128 + t / 2] = mcvt(d, thr);
      orow[t / 2] = mcvt(ap, thr);
    }
  }
}

// ---------------- Kernel 4: bf16 MFMA GEMM + ReLU, 512 threads ----------------
// C[8192x512] = relu( Am @ Wt^T ). Tile 128m x 64n, BK=64, 8 waves/block
// (wave tile 32x32). 512-thread blocks x 2 blocks/CU. 1-D grid of 512:
// xcd = id&7, mblk = (slot>>3)*8 + xcd -> all 8 n-blocks of an A-strip co-run
// on one XCD (A strip L2-resident). LDS XOR-8 chunk swizzle via DMA source
// address -> 2-way bank aliasing only.
//
// Round-5 change: T3-minimum double-buffered pipeline. Old loop was
// {stage -> syncthreads(full vmcnt drain) -> compute -> syncthreads}: load
// latency fully exposed every iteration. New loop stages tile t+1 into the
// other LDS buffer BEFORE computing tile t, drains vmcnt(0) AFTER the MFMA
// cluster, one raw s_barrier per iteration (64 barriers vs 128).
// Single-barrier correctness: all ds_reads of buf[cur] retire before the
// end-of-iter barrier (consumed by pre-barrier MFMAs); the STAGE that
// overwrites buf[cur] is only issued after that barrier (next iteration).
#define GEMM_COMPUTE(ASB, BSB)                                                        \
  {                                                                                   \
    short8 af[2][2], bf[2][2];                                                        \
    _Pragma("unroll")                                                                 \
    for (int mi = 0; mi < 2; ++mi) {                                                  \
      const int arow = wm * 32 + mi * 16 + l15;                                       \
      _Pragma("unroll")                                                               \
      for (int ks = 0; ks < 2; ++ks)                                                  \
        af[mi][ks] = *(const short8*)&(ASB)[arow * 64 + ((ks * 4 + quad) ^ (arow & 7)) * 8]; \
    }                                                                                 \
    _Pragma("unroll")                                                                 \
    for (int ni = 0; ni < 2; ++ni) {                                                  \
      const int brow = wn * 32 + ni * 16 + l15;                                       \
      _Pragma("unroll")                                                               \
      for (int ks = 0; ks < 2; ++ks)                                                  \
        bf[ni][ks] = *(const short8*)&(BSB)[brow * 64 + ((ks * 4 + quad) ^ (brow & 7)) * 8]; \
    }                                                                                 \
    _Pragma("unroll")                                                                 \
    for (int ks = 0; ks < 2; ++ks)                                                    \
      _Pragma("unroll")                                                               \
      for (int mi = 0; mi < 2; ++mi)                                                  \
        _Pragma("unroll")                                                             \
        for (int ni = 0; ni < 2; ++ni)                                                \
          acc[mi][ni] = __builtin_amdgcn_mfma_f32_16x16x32_bf16(af[mi][ks], bf[ni][ks], \
                                                                acc[mi][ni], 0, 0, 0); \
  }

__global__ __launch_bounds__(512) void gemm_kernel(const unsigned short* __restrict__ Am,
                                                   const unsigned short* __restrict__ Wt,
                                                   float* __restrict__ out) {
  __shared__ __align__(16) unsigned short As[2][128 * 64];  // 2 x 16 KB
  __shared__ __align__(16) unsigned short Bs[2][64 * 64];   // 2 x  8 KB

  const int tid = threadIdx.x;
  const int lane = tid & 63, w = tid >> 6;      // 8 waves
  const int quad = lane >> 4, l15 = lane & 15;
  const int wm = w >> 1, wn = w & 1;            // 4 x 2 wave grid

  const int id = blockIdx.x;
  const int xcd = id & 7, slot = id >> 3;
  const int nblk = slot & 7;
  const int mblk = (slot >> 3) * 8 + xcd;
  const int n0 = nblk * 64, m0 = mblk * 128;

  f32x4 acc[2][2] = {};

  const int rl = lane >> 3;            // row within an 8-row DMA group
  const int cg = (lane & 7) ^ rl;      // XOR-swizzled source chunk index
  const unsigned short* AgBase = Am + (size_t)(m0 + rl) * LDIM + cg * 8;
  const unsigned short* BgBase = Wt + (size_t)(n0 + rl) * LDIM + cg * 8;

  // per-wave STAGE of one K-tile into buffer `buf`
  // A: 128 rows, wave w covers rows (w*2+j)*8..+8, j=0,1; B: 64 rows, wave w
  // covers rows w*8..+8. 3 async16 per wave per tile.
#define GEMM_STAGE(buf, k0)                                                            \
  {                                                                                    \
    _Pragma("unroll")                                                                  \
    for (int j = 0; j < 2; ++j)                                                        \
      async16(&As[buf][(w * 2 + j) * 512], AgBase + (size_t)((w * 2 + j) * 8) * LDIM + (k0)); \
    async16(&Bs[buf][w * 512], BgBase + (size_t)(w * 8) * LDIM + (k0));                \
  }

  // prologue: stage tile 0, wait, barrier
  GEMM_STAGE(0, 0);
  asm volatile("s_waitcnt vmcnt(0)" ::: "memory");
  __builtin_amdgcn_s_barrier();
  __builtin_amdgcn_sched_barrier(0);

  int cur = 0;
  for (int t = 0; t < (LDIM / 64) - 1; ++t) {
    // issue next tile's loads first — they fly during ds_read + MFMA below
    GEMM_STAGE(cur ^ 1, (t + 1) * 64);
    GEMM_COMPUTE(As[cur], Bs[cur]);
    // drain own loads (mostly landed by now), then one barrier
    asm volatile("s_waitcnt vmcnt(0)" ::: "memory");
    __builtin_amdgcn_s_barrier();
    __builtin_amdgcn_sched_barrier(0);
    cur ^= 1;
  }
  // epilogue iteration: no prefetch
  GEMM_COMPUTE(As[cur], Bs[cur]);

  // C/D layout: col = lane&15, row = quad*4 + reg (verified rounds 1-4)
#pragma unroll
  for (int mi = 0; mi < 2; ++mi) {
#pragma unroll
    for (int ni = 0; ni < 2; ++ni) {
      const int r0 = m0 + wm * 32 + mi * 16 + quad * 4;
      const int c = n0 + wn * 32 + ni * 16 + l15;
#pragma unroll
      for (int r = 0; r < 4; ++r)
        out[(size_t)(r0 + r) * NOUT + c] = fmaxf(acc[mi][ni][r], 0.0f);
    }
  }
}

extern "C" void kernel_launch(void* const* d_in, const int* in_sizes, int n_in,
                              void* d_out, int out_size, void* d_ws, size_t ws_size,
                              hipStream_t stream) {
  const float* x = (const float*)d_in[0];
  const float* W = (const float*)d_in[1];
  float* out = (float*)d_out;

  char* ws = (char*)d_ws;
  unsigned short* Am = (unsigned short*)(ws + AM_OFF);
  unsigned short* Wt = (unsigned short*)(ws + WT_OFF);
  double* partials = (double*)(ws + PART_OFF);
  float* thr = (float*)(ws + THR_OFF);

  haar1_kernel<<<NROWS + 2048, 256, 0, stream>>>(x, partials, W, Wt);
  thr_kernel<<<1, 1024, 0, stream>>>(partials, thr);
  haar2_kernel<<<NROWS, 256, 0, stream>>>(x, thr, Am);
  gemm_kernel<<<512, 512, 0, stream>>>(Am, Wt, out);
}